// Round 1
// baseline (40079.022 us; speedup 1.0000x reference)
//
#include <hip/hip_runtime.h>
#include <math.h>

#define BATCH   16
#define SEQ     768
#define DMODEL  512
#define DSTATE  128
#define DINNER  1024
#define NHEADS  16
#define HEADDIM 64
#define CONVDIM 1280            // DINNER + 2*DSTATE
#define DINPROJ 2320            // 2*DINNER + 2*DSTATE + NHEADS
#define NLAYER  28
#define VOCABSZ 256
#define NROWS   (BATCH*SEQ)     // 12288
#define EPSV    1e-5f

__device__ __forceinline__ float siluf(float v) { return v / (1.f + expf(-v)); }

// ---------------- embedding gather ----------------
__global__ __launch_bounds__(256) void embed_kernel(const int* __restrict__ tok,
    const float* __restrict__ emb, float* __restrict__ hid) {
  int i = blockIdx.x * 256 + threadIdx.x;
  if (i >= NROWS * DMODEL) return;
  int r = i >> 9;               // / DMODEL
  int d = i & (DMODEL - 1);
  hid[i] = emb[(size_t)tok[r] * DMODEL + d];
}

// ---------------- residual add + RMSNorm (512 cols) ----------------
// res = h + res (written back); xn = rms(res) * w
__global__ __launch_bounds__(128) void prenorm_kernel(const float* __restrict__ h,
    float* __restrict__ res, const float* __restrict__ w, float* __restrict__ xn) {
  int row = blockIdx.x;
  int tid = threadIdx.x;        // 128 threads, one float4 each (512 cols)
  const float4* h4 = (const float4*)(h + (size_t)row * DMODEL);
  float4* r4 = (float4*)(res + (size_t)row * DMODEL);
  float4 v = r4[tid];
  float4 a = h4[tid];
  v.x += a.x; v.y += a.y; v.z += a.z; v.w += a.w;
  r4[tid] = v;
  float ss = v.x * v.x + v.y * v.y + v.z * v.z + v.w * v.w;
  #pragma unroll
  for (int o = 32; o > 0; o >>= 1) ss += __shfl_down(ss, o);
  __shared__ float wred[2];
  if ((tid & 63) == 0) wred[tid >> 6] = ss;
  __syncthreads();
  float tot = wred[0] + wred[1];
  float scale = rsqrtf(tot / (float)DMODEL + EPSV);
  const float4* w4 = (const float4*)w;
  float4 wv = w4[tid];
  float4 o4;
  o4.x = v.x * scale * wv.x; o4.y = v.y * scale * wv.y;
  o4.z = v.z * scale * wv.z; o4.w = v.w * scale * wv.w;
  ((float4*)(xn + (size_t)row * DMODEL))[tid] = o4;
}

// ---------------- generic fp32 GEMM: C[M,N] = A[M,K] * B[N,K]^T ----------------
#define GBM 64
#define GBN 64
#define GBK 16
__global__ __launch_bounds__(256) void gemm_bt(const float* __restrict__ A,
    const float* __restrict__ B, float* __restrict__ C, int M, int N, int K) {
  __shared__ float As[GBK][GBM + 4];
  __shared__ float Bs[GBK][GBN + 4];
  int tid = threadIdx.x;
  int m0 = blockIdx.y * GBM;
  int n0 = blockIdx.x * GBN;
  int tx = tid & 15, ty = tid >> 4;
  int lrow = tid >> 2;            // 0..63
  int lk = (tid & 3) * 4;         // 0,4,8,12
  float acc[4][4] = {};
  for (int k0 = 0; k0 < K; k0 += GBK) {
    float4 av = *(const float4*)(A + (size_t)(m0 + lrow) * K + k0 + lk);
    int bn = n0 + lrow;
    float4 bv = make_float4(0.f, 0.f, 0.f, 0.f);
    if (bn < N) bv = *(const float4*)(B + (size_t)bn * K + k0 + lk);
    As[lk + 0][lrow] = av.x; As[lk + 1][lrow] = av.y;
    As[lk + 2][lrow] = av.z; As[lk + 3][lrow] = av.w;
    Bs[lk + 0][lrow] = bv.x; Bs[lk + 1][lrow] = bv.y;
    Bs[lk + 2][lrow] = bv.z; Bs[lk + 3][lrow] = bv.w;
    __syncthreads();
    #pragma unroll
    for (int k = 0; k < GBK; ++k) {
      float4 a = *(const float4*)&As[k][ty * 4];
      float4 bq = *(const float4*)&Bs[k][tx * 4];
      float avx[4] = {a.x, a.y, a.z, a.w};
      float bvx[4] = {bq.x, bq.y, bq.z, bq.w};
      #pragma unroll
      for (int i = 0; i < 4; ++i)
        #pragma unroll
        for (int j = 0; j < 4; ++j)
          acc[i][j] += avx[i] * bvx[j];
    }
    __syncthreads();
  }
  #pragma unroll
  for (int i = 0; i < 4; ++i) {
    int m = m0 + ty * 4 + i;
    int n = n0 + tx * 4;
    if (n < N)
      *(float4*)(C + (size_t)m * N + n) =
          make_float4(acc[i][0], acc[i][1], acc[i][2], acc[i][3]);
  }
}

// ---------------- dt = softplus(raw + bias); dA = exp(dt * A) ----------------
__global__ __launch_bounds__(256) void dt_kernel(const float* __restrict__ zx,
    const float* __restrict__ dt_bias, const float* __restrict__ A_log,
    float* __restrict__ dt, float* __restrict__ dA) {
  int i = blockIdx.x * 256 + threadIdx.x;
  if (i >= NROWS * NHEADS) return;
  int h = i & (NHEADS - 1);
  int row = i >> 4;
  float v = zx[(size_t)row * DINPROJ + (DINNER + CONVDIM) + h] + dt_bias[h];
  float sp = fmaxf(v, 0.f) + log1pf(expf(-fabsf(v)));
  float Ah = -expf(A_log[h]);
  dt[i] = sp;
  dA[i] = expf(sp * Ah);
}

// ---------------- causal conv (width 4) + silu ----------------
__global__ __launch_bounds__(256) void conv_kernel(const float* __restrict__ zx,
    const float* __restrict__ cw, const float* __restrict__ cb, float* __restrict__ out) {
  int c = blockIdx.x * 256 + threadIdx.x;      // 0..1279
  int bl = blockIdx.y;                         // 0..NROWS-1
  int t = bl % SEQ;
  float acc = cb[c];
  #pragma unroll
  for (int k = 0; k < 4; ++k) {
    int tt = t + k - 3;
    if (tt >= 0)
      acc += zx[(size_t)(bl + k - 3) * DINPROJ + DINNER + c] * cw[c * 4 + k];
  }
  out[(size_t)bl * CONVDIM + c] = siluf(acc);
}

// ---------------- SSD scan: one workgroup per (b,h), 4 waves n-split ----------------
__global__ __launch_bounds__(256) void scan_kernel(const float* __restrict__ conv,
    const float* __restrict__ dtb, const float* __restrict__ dAb,
    const float* __restrict__ Dp, float* __restrict__ y) {
  int bh = blockIdx.x;
  int b = bh >> 4, h = bh & 15;
  int tid = threadIdx.x;
  int s = tid >> 6;               // wave id: n-slice [32s, 32s+32)
  int p = tid & 63;               // lane = headdim index
  float hs[32];
  #pragma unroll
  for (int j = 0; j < 32; ++j) hs[j] = 0.f;
  float Dh = Dp[h];
  __shared__ float yred[8][4][64];
  const int nbase = DINNER + s * 32;
  for (int t0 = 0; t0 < SEQ; t0 += 8) {
    #pragma unroll 1
    for (int tc = 0; tc < 8; ++tc) {
      int t = t0 + tc;
      size_t rbase = (size_t)(b * SEQ + t) * CONVDIM;
      float x = conv[rbase + h * HEADDIM + p];
      int dti = (b * SEQ + t) * NHEADS + h;
      float dtv = dtb[dti];
      float dAv = dAb[dti];
      float dtx = dtv * x;
      const float4* Bp = (const float4*)(conv + rbase + nbase);
      const float4* Cp = (const float4*)(conv + rbase + nbase + DSTATE);
      float y0 = 0.f, y1 = 0.f, y2 = 0.f, y3 = 0.f;
      #pragma unroll
      for (int q = 0; q < 8; ++q) {
        float4 Bv = Bp[q];
        float4 Cv = Cp[q];
        hs[q * 4 + 0] = dAv * hs[q * 4 + 0] + dtx * Bv.x; y0 += hs[q * 4 + 0] * Cv.x;
        hs[q * 4 + 1] = dAv * hs[q * 4 + 1] + dtx * Bv.y; y1 += hs[q * 4 + 1] * Cv.y;
        hs[q * 4 + 2] = dAv * hs[q * 4 + 2] + dtx * Bv.z; y2 += hs[q * 4 + 2] * Cv.z;
        hs[q * 4 + 3] = dAv * hs[q * 4 + 3] + dtx * Bv.w; y3 += hs[q * 4 + 3] * Cv.w;
      }
      float yp = (y0 + y1) + (y2 + y3);
      if (s == 0) yp += Dh * x;
      yred[tc][s][p] = yp;
    }
    __syncthreads();
    for (int i = tid; i < 512; i += 256) {
      int tc = i >> 6, pp = i & 63;
      float v = yred[tc][0][pp] + yred[tc][1][pp] + yred[tc][2][pp] + yred[tc][3][pp];
      y[((size_t)(b * SEQ + t0 + tc) * NHEADS + h) * HEADDIM + pp] = v;
    }
    __syncthreads();
  }
}

// ---------------- gated RMSNorm over 1024 ----------------
__global__ __launch_bounds__(256) void gated_norm_kernel(const float* __restrict__ y,
    const float* __restrict__ zx, const float* __restrict__ gw, float* __restrict__ out) {
  int row = blockIdx.x;
  int tid = threadIdx.x;          // 256 threads, one float4 each (1024 cols)
  const float4* y4 = (const float4*)(y + (size_t)row * DINNER);
  const float4* z4 = (const float4*)(zx + (size_t)row * DINPROJ);
  float4 yv = y4[tid];
  float4 zv = z4[tid];
  float4 g;
  g.x = yv.x * siluf(zv.x); g.y = yv.y * siluf(zv.y);
  g.z = yv.z * siluf(zv.z); g.w = yv.w * siluf(zv.w);
  float ss = g.x * g.x + g.y * g.y + g.z * g.z + g.w * g.w;
  #pragma unroll
  for (int o = 32; o > 0; o >>= 1) ss += __shfl_down(ss, o);
  __shared__ float red[4];
  if ((tid & 63) == 0) red[tid >> 6] = ss;
  __syncthreads();
  float tot = red[0] + red[1] + red[2] + red[3];
  float scale = rsqrtf(tot / (float)DINNER + EPSV);
  const float4* g4 = (const float4*)gw;
  float4 wv = g4[tid];
  float4 o4;
  o4.x = g.x * scale * wv.x; o4.y = g.y * scale * wv.y;
  o4.z = g.z * scale * wv.z; o4.w = g.w * scale * wv.w;
  ((float4*)(out + (size_t)row * DINNER))[tid] = o4;
}

// ---------------- per-row loss: lse - logit[target] ----------------
__global__ __launch_bounds__(256) void rowloss_kernel(const float* __restrict__ logits,
    const int* __restrict__ targets, float* __restrict__ rl) {
  int row = blockIdx.x * 4 + (threadIdx.x >> 6);
  int lane = threadIdx.x & 63;
  const float* lr = logits + (size_t)row * VOCABSZ;
  float4 v = ((const float4*)lr)[lane];
  float mx = fmaxf(fmaxf(v.x, v.y), fmaxf(v.z, v.w));
  #pragma unroll
  for (int o = 32; o > 0; o >>= 1) mx = fmaxf(mx, __shfl_down(mx, o));
  mx = __shfl(mx, 0);
  float e = expf(v.x - mx) + expf(v.y - mx) + expf(v.z - mx) + expf(v.w - mx);
  #pragma unroll
  for (int o = 32; o > 0; o >>= 1) e += __shfl_down(e, o);
  if (lane == 0) {
    float lse = logf(e) + mx;
    rl[row] = lse - lr[targets[row]];
  }
}

__global__ __launch_bounds__(256) void loss_reduce_kernel(const float* __restrict__ rl,
    float* __restrict__ out) {
  int tid = threadIdx.x;
  float ssum = 0.f;
  for (int i = tid; i < NROWS; i += 256) ssum += rl[i];
  #pragma unroll
  for (int o = 32; o > 0; o >>= 1) ssum += __shfl_down(ssum, o);
  __shared__ float red[4];
  if ((tid & 63) == 0) red[tid >> 6] = ssum;
  __syncthreads();
  if (tid == 0) out[0] = (red[0] + red[1] + red[2] + red[3]) / (float)NROWS;
}

extern "C" void kernel_launch(void* const* d_in, const int* in_sizes, int n_in,
                              void* d_out, int out_size, void* d_ws, size_t ws_size,
                              hipStream_t stream) {
  const int*   tokens       = (const int*)d_in[0];
  const int*   targets      = (const int*)d_in[1];
  const float* embedding    = (const float*)d_in[2];
  const float* in_proj_w    = (const float*)d_in[3];
  const float* conv_w       = (const float*)d_in[4];
  const float* conv_b       = (const float*)d_in[5];
  const float* dt_bias      = (const float*)d_in[6];
  const float* A_log        = (const float*)d_in[7];
  const float* Dp           = (const float*)d_in[8];
  const float* gnorm_w      = (const float*)d_in[9];
  const float* out_proj_w   = (const float*)d_in[10];
  const float* block_norm_w = (const float*)d_in[11];
  const float* norm_f_w     = (const float*)d_in[12];
  float* out = (float*)d_out;

  float* ws = (float*)d_ws;
  size_t off = 0;
  float* hidden   = ws + off; off += (size_t)NROWS * DMODEL;
  float* residual = ws + off; off += (size_t)NROWS * DMODEL;
  float* xn       = ws + off; off += (size_t)NROWS * DMODEL;
  float* zx       = ws + off; off += (size_t)NROWS * DINPROJ;
  float* convo    = ws + off; off += (size_t)NROWS * CONVDIM;
  float* dtb      = ws + off; off += (size_t)NROWS * NHEADS;
  float* dAb      = ws + off; off += (size_t)NROWS * NHEADS;
  float* ybuf     = ws + off; off += (size_t)NROWS * DINNER;
  float* ynorm    = ws + off; off += (size_t)NROWS * DINNER;
  float* rowloss  = ws + off; off += NROWS;

  hipMemsetAsync(residual, 0, (size_t)NROWS * DMODEL * sizeof(float), stream);
  embed_kernel<<<NROWS * DMODEL / 256, 256, 0, stream>>>(tokens, embedding, hidden);

  for (int l = 0; l < NLAYER; ++l) {
    const float* ipw = in_proj_w + (size_t)l * DINPROJ * DMODEL;
    const float* cw  = conv_w + (size_t)l * CONVDIM * 4;
    const float* cb  = conv_b + (size_t)l * CONVDIM;
    const float* dtbias_l = dt_bias + (size_t)l * NHEADS;
    const float* alog_l   = A_log + (size_t)l * NHEADS;
    const float* D_l      = Dp + (size_t)l * NHEADS;
    const float* gw  = gnorm_w + (size_t)l * DINNER;
    const float* opw = out_proj_w + (size_t)l * DMODEL * DINNER;
    const float* bnw = block_norm_w + (size_t)l * DMODEL;

    prenorm_kernel<<<NROWS, 128, 0, stream>>>(hidden, residual, bnw, xn);
    dim3 g1((DINPROJ + GBN - 1) / GBN, NROWS / GBM);
    gemm_bt<<<g1, 256, 0, stream>>>(xn, ipw, zx, NROWS, DINPROJ, DMODEL);
    dt_kernel<<<(NROWS * NHEADS) / 256, 256, 0, stream>>>(zx, dtbias_l, alog_l, dtb, dAb);
    conv_kernel<<<dim3(CONVDIM / 256, NROWS), 256, 0, stream>>>(zx, cw, cb, convo);
    scan_kernel<<<BATCH * NHEADS, 256, 0, stream>>>(convo, dtb, dAb, D_l, ybuf);
    gated_norm_kernel<<<NROWS, 256, 0, stream>>>(ybuf, zx, gw, ynorm);
    dim3 g2(DMODEL / GBN, NROWS / GBM);
    gemm_bt<<<g2, 256, 0, stream>>>(ynorm, opw, hidden, NROWS, DMODEL, DINNER);
  }

  prenorm_kernel<<<NROWS, 128, 0, stream>>>(hidden, residual, norm_f_w, xn);
  dim3 g3(VOCABSZ / GBN, NROWS / GBM);
  gemm_bt<<<g3, 256, 0, stream>>>(xn, embedding, out, NROWS, VOCABSZ, DMODEL);
  rowloss_kernel<<<NROWS / 4, 256, 0, stream>>>(out, targets, rowloss);
  loss_reduce_kernel<<<1, 256, 0, stream>>>(rowloss, out + (size_t)(out_size - 1));
}